// Round 17
// baseline (79.754 us; speedup 1.0000x reference)
//
#include <hip/hip_runtime.h>
#include <hip/hip_bf16.h>
#include <math.h>

#define B 4
#define L 1024
#define D 256
#define H 8
#define HD 64

// workspace layout (float offsets)
#define KB_OFF  1048576                // Q bf16 [0, KB_OFF) floats
#define VR_OFF  2097152                // K bf16 [KB_OFF, VR_OFF); lvr fp32 here
#define GS0_OFF (VR_OFF + 32768)       // denom partial khalf0 (plain stores)
#define GS1_OFF (GS0_OFF + 32768)      // denom partial khalf1
#define DP_OFF  (GS1_OFF + 32768)      // Dpart fp32 [hb][chunk 144][64] (1.2 MB)
#define XP_OFF  (DP_OFF + 294912)      // xpe bf16 [4096][256]
#define WT_OFF  (XP_OFF + 524288)      // WT bf16 [1024][256]
// total floats: WT_OFF + 131072 = 3276800 (~13.1 MB)

typedef short short8 __attribute__((ext_vector_type(8)));
typedef float f32x16 __attribute__((ext_vector_type(16)));

__device__ __forceinline__ unsigned short f2bf(float f) {
  __hip_bfloat16 h = __float2bfloat16(f);
  return *reinterpret_cast<unsigned short*>(&h);
}

// ---------------------------------------------------------------------------
// prep_wx: Blocks 0..31: WT transpose. Blocks 32..543: XP = bf16(x+pe);
//          lvr[hb][k] = log2(sigmoid(x@Wv)) reversed.
// ---------------------------------------------------------------------------
__global__ __launch_bounds__(256) void prep_wx_kernel(
    const float* __restrict__ x, const float* __restrict__ Wq,
    const float* __restrict__ Wk, const float* __restrict__ Wv,
    const float* __restrict__ pe, float* __restrict__ ws)
{
  const int tid = threadIdx.x;
  if (blockIdx.x < 32) {
    __shared__ float lds[32][257];
    const int c0 = blockIdx.x * 32;
    const float* W = (c0 < 512) ? Wq : Wk;
    const int cc = c0 & 511;
    const int c = tid & 31, dd = tid >> 5;
    for (int d0 = 0; d0 < 256; d0 += 8)
      lds[c][d0 + dd] = W[(d0 + dd) * 512 + cc + c];
    __syncthreads();
    __hip_bfloat16* WT = (__hip_bfloat16*)(ws + WT_OFF);
    for (int cl = 0; cl < 32; ++cl)
      WT[(c0 + cl) * 256 + tid] = __float2bfloat16(lds[cl][tid]);
    return;
  }

  __shared__ float xs[8][257];
  const int r0 = (blockIdx.x - 32) * 8;
  __hip_bfloat16* XP = (__hip_bfloat16*)(ws + XP_OFF);
  for (int idx = tid; idx < 2048; idx += 256) {
    int rr = idx >> 8, c = idx & 255;
    int gr = r0 + rr, l = gr & 1023;
    float xv = x[gr * 256 + c];
    xs[rr][c] = xv;
    XP[gr * 256 + c] = __float2bfloat16(xv + pe[l * 256 + c]);
  }
  __syncthreads();
  if (tid < 64) {
    int rr = tid >> 3, h = tid & 7;
    float acc = 0.f;
    for (int d = 0; d < 256; ++d) acc += xs[rr][d] * Wv[d * 8 + h];
    float v = 1.f / (1.f + __expf(-acc));
    int gr = r0 + rr;
    int b = gr >> 10, l = gr & 1023;
    ws[VR_OFF + (h * 4 + b) * 1024 + (1023 - l)] = __log2f(v);
  }
}

// ---------------------------------------------------------------------------
// qkgemm: Q|K = bf16(XP @ [Wq|Wk] + bias) via MFMA, written to [hb][l][64].
// ---------------------------------------------------------------------------
__global__ __launch_bounds__(256) void qkgemm_kernel(float* __restrict__ ws,
    const float* __restrict__ bq, const float* __restrict__ bk)
{
  const int tid = threadIdx.x;
  const int w = tid >> 6, lane = tid & 63;
  const int wid = blockIdx.x * 4 + w;
  const int lt = wid & 127;
  const int cp = wid >> 7;           // 0..15 (0..7 -> Q, 8..15 -> K)

  const __hip_bfloat16* XP = (const __hip_bfloat16*)(ws + XP_OFF);
  const __hip_bfloat16* WT = (const __hip_bfloat16*)(ws + WT_OFF);

  const int ln = (lt << 5) + (lane & 31);
  const int dlo = (lane >> 5) << 3;
  const int ca = (cp << 6) + (lane & 31);
  const __hip_bfloat16* xr = XP + ln * 256 + dlo;
  const __hip_bfloat16* ar = WT + ca * 256 + dlo;
  const __hip_bfloat16* br = ar + (32 * 256);

  f32x16 acca = {0.f,0.f,0.f,0.f,0.f,0.f,0.f,0.f,0.f,0.f,0.f,0.f,0.f,0.f,0.f,0.f};
  f32x16 accb = {0.f,0.f,0.f,0.f,0.f,0.f,0.f,0.f,0.f,0.f,0.f,0.f,0.f,0.f,0.f,0.f};
#pragma unroll
  for (int k = 0; k < 16; ++k) {
    short8 bf  = *(const short8*)(xr + k * 16);
    short8 afa = *(const short8*)(ar + k * 16);
    short8 afb = *(const short8*)(br + k * 16);
    acca = __builtin_amdgcn_mfma_f32_32x32x16_bf16(afa, bf, acca, 0, 0, 0);
    accb = __builtin_amdgcn_mfma_f32_32x32x16_bf16(afb, bf, accb, 0, 0, 0);
  }

  const int b = ln >> 10, l = ln & 1023;
  const int hq = cp & 7;
  const int hi4 = (lane >> 5) << 2;
  const float* bias = (cp < 8) ? bq : bk;
  const int cbase = hq << 6;
  __hip_bfloat16* base = (__hip_bfloat16*)ws + ((cp < 8) ? 0 : (size_t)KB_OFF * 2);
  __hip_bfloat16* dst = base + ((((size_t)(hq * 4 + b) << 10) + l) << 6);

#pragma unroll
  for (int q = 0; q < 4; ++q) {
    int hd0 = (q << 3) + hi4;
    float4 bv = *(const float4*)(bias + cbase + hd0);
    ushort4 pk;
    pk.x = f2bf(acca[4 * q + 0] + bv.x);
    pk.y = f2bf(acca[4 * q + 1] + bv.y);
    pk.z = f2bf(acca[4 * q + 2] + bv.z);
    pk.w = f2bf(acca[4 * q + 3] + bv.w);
    *(ushort4*)(dst + hd0) = pk;

    int hd1 = hd0 + 32;
    float4 bw = *(const float4*)(bias + cbase + hd1);
    ushort4 pk2;
    pk2.x = f2bf(accb[4 * q + 0] + bw.x);
    pk2.y = f2bf(accb[4 * q + 1] + bw.y);
    pk2.z = f2bf(accb[4 * q + 2] + bw.z);
    pk2.w = f2bf(accb[4 * q + 3] + bw.w);
    *(ushort4*)(dst + hd1) = pk2;
  }
}

// ---------------------------------------------------------------------------
// gsum: single-pass FOUR-CHAIN. Wave w computes its 4 k-tiles
// {w, w+4, w+8, w+12} (+khalf*16) concurrently: 16 loads in flight, 4
// independent MFMA chains -> one latency round. Plain stores, no atomics.
// Grid 2048 = (khalf 2) x (qt 32) x (hb 32).
// ---------------------------------------------------------------------------
__global__ __launch_bounds__(256) void gsum_kernel(float* __restrict__ ws)
{
  __shared__ float smerge[4][32];
  const int tid = threadIdx.x;
  const int w = tid >> 6, lane = tid & 63;
  const int i = blockIdx.x;
  const int hb = i & 31;
  const int qt = (i >> 5) & 31;
  const int khalf = i >> 10;

  const __hip_bfloat16* Qb = (const __hip_bfloat16*)ws + ((size_t)hb << 16);
  const __hip_bfloat16* Kb = (const __hip_bfloat16*)(ws + KB_OFF) + ((size_t)hb << 16);

  const int q0 = qt << 5;
  const int qrow = q0 + (lane & 31);
  const int dlo = (lane >> 5) << 3;

  const __hip_bfloat16* qr = Qb + (qrow << 6) + dlo;
  short8 qf0 = *(const short8*)(qr);
  short8 qf1 = *(const short8*)(qr + 16);
  short8 qf2 = *(const short8*)(qr + 32);
  short8 qf3 = *(const short8*)(qr + 48);

#define GLOADK(kt, kf)                                                        \
  {                                                                           \
    const __hip_bfloat16* kr_ = Kb + ((((kt) << 5) + (lane & 31)) << 6) + dlo;\
    kf[0] = *(const short8*)(kr_);                                            \
    kf[1] = *(const short8*)(kr_ + 16);                                       \
    kf[2] = *(const short8*)(kr_ + 32);                                       \
    kf[3] = *(const short8*)(kr_ + 48);                                       \
  }

  const int kt0 = (khalf << 4) + w;
  short8 kA[4], kB[4], kC[4], kD[4];
  GLOADK(kt0, kA);
  GLOADK(kt0 + 4, kB);
  GLOADK(kt0 + 8, kC);
  GLOADK(kt0 + 12, kD);

  f32x16 aA = {0.f,0.f,0.f,0.f,0.f,0.f,0.f,0.f,0.f,0.f,0.f,0.f,0.f,0.f,0.f,0.f};
  f32x16 aB = {0.f,0.f,0.f,0.f,0.f,0.f,0.f,0.f,0.f,0.f,0.f,0.f,0.f,0.f,0.f,0.f};
  f32x16 aC = {0.f,0.f,0.f,0.f,0.f,0.f,0.f,0.f,0.f,0.f,0.f,0.f,0.f,0.f,0.f,0.f};
  f32x16 aD = {0.f,0.f,0.f,0.f,0.f,0.f,0.f,0.f,0.f,0.f,0.f,0.f,0.f,0.f,0.f,0.f};
#pragma unroll
  for (int s = 0; s < 4; ++s) {
    short8 qs = (s == 0) ? qf0 : (s == 1) ? qf1 : (s == 2) ? qf2 : qf3;
    aA = __builtin_amdgcn_mfma_f32_32x32x16_bf16(kA[s], qs, aA, 0, 0, 0);
    aB = __builtin_amdgcn_mfma_f32_32x32x16_bf16(kB[s], qs, aB, 0, 0, 0);
    aC = __builtin_amdgcn_mfma_f32_32x32x16_bf16(kC[s], qs, aC, 0, 0, 0);
    aD = __builtin_amdgcn_mfma_f32_32x32x16_bf16(kD[s], qs, aD, 0, 0, 0);
  }

  float s0 = 0.f, s1 = 0.f, s2 = 0.f, s3 = 0.f;
#pragma unroll
  for (int r = 0; r < 16; ++r) {
    s0 += __expf(aA[r] * 0.125f);
    s1 += __expf(aB[r] * 0.125f);
    s2 += __expf(aC[r] * 0.125f);
    s3 += __expf(aD[r] * 0.125f);
  }
  float s_part = (s0 + s1) + (s2 + s3);
  s_part += __shfl_xor(s_part, 32);
  if (lane < 32) smerge[w][lane] = s_part;
  __syncthreads();
  if (tid < 32) {
    float s = smerge[0][tid] + smerge[1][tid] + smerge[2][tid] + smerge[3][tid];
    ws[(khalf ? GS1_OFF : GS0_OFF) + (hb << 10) + q0 + tid] = s;
  }
}

// ---------------------------------------------------------------------------
// diag: r16 structure + PREDICATED loop (no data-dependent break) so the
// compiler can overlap all 4 iterations' loads. Zero-atomic LDS flush.
// Grid 1152 = (cgroup 36) x (hb 32); hb = i&31 -> XCD-pinned.
// ---------------------------------------------------------------------------
__global__ __launch_bounds__(256) void diag_kernel(float* __restrict__ ws)
{
  __shared__ float V[4][64][17];    // 17.4 KB
  const int tid = threadIdx.x;
  const int w = tid >> 6, lane = tid & 63;
  const int i = blockIdx.x;
  const int hb = i & 31;
  const int cg = i >> 5;            // 0..35
  const int chunk = cg * 4 + w;     // 0..143

  // decode chunk -> (dt, qt0): chunks per diagonal = (35-dt)>>2
  int dt = 0, cum = 0;
  for (;;) {
    int n = (35 - dt) >> 2;
    if (chunk < cum + n) break;
    cum += n; ++dt;
  }
  const int qt0 = (chunk - cum) << 2;
  const int qtmax = 31 - dt;

  const __hip_bfloat16* Qb = (const __hip_bfloat16*)ws + ((size_t)hb << 16);
  const __hip_bfloat16* Kb = (const __hip_bfloat16*)(ws + KB_OFF) + ((size_t)hb << 16);
  const float* __restrict__ gs0 = ws + GS0_OFF + (hb << 10);
  const float* __restrict__ gs1 = ws + GS1_OFF + (hb << 10);
  const float* __restrict__ lvr = ws + VR_OFF + (hb << 10);

  const int dlo = (lane >> 5) << 3;
  const int coff = (lane >> 5) << 2;

  float accT[16];
#pragma unroll
  for (int r = 0; r < 16; ++r) accT[r] = 0.f;

#pragma unroll
  for (int u = 0; u < 4; ++u) {
    const int qtv = qt0 + u;
    const float gate = (qtv <= qtmax) ? 1.f : 0.f;
    const int qt = (qtv <= qtmax) ? qtv : qtmax;   // clamp: safe addresses
    const int kt = qt + dt;
    const int qrow = (qt << 5) + (lane & 31);
    const __hip_bfloat16* qr = Qb + (qrow << 6) + dlo;
    const __hip_bfloat16* kr = Kb + (((kt << 5) + (lane & 31)) << 6) + dlo;
    short8 qf0 = *(const short8*)(qr);
    short8 qf1 = *(const short8*)(qr + 16);
    short8 qf2 = *(const short8*)(qr + 32);
    short8 qf3 = *(const short8*)(qr + 48);
    short8 kf0 = *(const short8*)(kr);
    short8 kf1 = *(const short8*)(kr + 16);
    short8 kf2 = *(const short8*)(kr + 32);
    short8 kf3 = *(const short8*)(kr + 48);
    const float* lb = lvr + (kt << 5) + coff;
    float4 lv0 = *(const float4*)(lb);
    float4 lv1 = *(const float4*)(lb + 8);
    float4 lv2 = *(const float4*)(lb + 16);
    float4 lv3 = *(const float4*)(lb + 24);
    float l2g = __log2f(gs0[qrow] + gs1[qrow]);

    f32x16 acc = {0.f,0.f,0.f,0.f,0.f,0.f,0.f,0.f,0.f,0.f,0.f,0.f,0.f,0.f,0.f,0.f};
    acc = __builtin_amdgcn_mfma_f32_32x32x16_bf16(kf0, qf0, acc, 0, 0, 0);
    acc = __builtin_amdgcn_mfma_f32_32x32x16_bf16(kf1, qf1, acc, 0, 0, 0);
    acc = __builtin_amdgcn_mfma_f32_32x32x16_bf16(kf2, qf2, acc, 0, 0, 0);
    acc = __builtin_amdgcn_mfma_f32_32x32x16_bf16(kf3, qf3, acc, 0, 0, 0);

    const float c = 0.125f * 1.44269504f;
#pragma unroll
    for (int r = 0; r < 4; ++r) accT[r]      += gate * exp2f(acc[r]      * c + (&lv0.x)[r] - l2g);
#pragma unroll
    for (int r = 0; r < 4; ++r) accT[r + 4]  += gate * exp2f(acc[r + 4]  * c + (&lv1.x)[r] - l2g);
#pragma unroll
    for (int r = 0; r < 4; ++r) accT[r + 8]  += gate * exp2f(acc[r + 8]  * c + (&lv2.x)[r] - l2g);
#pragma unroll
    for (int r = 0; r < 4; ++r) accT[r + 12] += gate * exp2f(acc[r + 12] * c + (&lv3.x)[r] - l2g);
  }

  // flush, zero atomics: plain write per-lane values, then per-slot gather.
#pragma unroll
  for (int r = 0; r < 16; ++r) V[w][lane][r] = accT[r];
  float acc = 0.f;
#pragma unroll
  for (int hi = 0; hi < 2; ++hi)
#pragma unroll
    for (int r = 0; r < 16; ++r) {
      int l = (hi << 2) + (r & 3) + ((r >> 2) << 3) + 31 - lane;
      if (l >= 0 && l < 32) acc += V[w][(hi << 5) + l][r];
    }
  ws[DP_OFF + (((hb * 144) + chunk) << 6) + lane] = acc;
}

// ---------------------------------------------------------------------------
// out: T[hb][j] = sum over contributing Dpart segments; window3 / cnt.
// Grid 256 = (jc 8) x (hb 32).
// ---------------------------------------------------------------------------
__global__ __launch_bounds__(256) void out_kernel(const float* __restrict__ ws,
                                                  float* __restrict__ out)
{
  __shared__ float s[130];
  const int tid = threadIdx.x;
  const int i = blockIdx.x;
  const int hb = i & 31;
  const int jc = i >> 5;
  const int j0 = jc << 7;
  const float* DP = ws + DP_OFF + ((hb * 144) << 6);

  if (tid < 130) {
    int jj = j0 + tid - 1;
    float acc = 0.f;
    if (jj >= 0 && jj < 1024) {
      int dthi = (jj + 31) >> 5;
#pragma unroll
      for (int cand = 0; cand < 2; ++cand) {
        int dt = dthi - cand;
        if (dt < 0 || dt > 31) continue;
        int idx = jj - (dt << 5) + 31;
        if (idx < 0 || idx > 62) continue;
        int base = 0;
        for (int d = 0; d < dt; ++d) base += (35 - d) >> 2;
        int nq = (35 - dt) >> 2;
        for (int qc = 0; qc < nq; ++qc)
          acc += DP[((base + qc) << 6) + idx];
      }
    }
    s[tid] = acc;
  }
  __syncthreads();
  if (tid < 128) {
    int j = j0 + tid;
    float cnt = (j == 0 || j == 1023) ? 2.f : 3.f;
    float v = (s[tid] + s[tid + 1] + s[tid + 2]) / cnt;
    int h = hb >> 2, b = hb & 3;
    out[(((b << 10) + j) << 3) + h] = v;
  }
}

extern "C" void kernel_launch(void* const* d_in, const int* in_sizes, int n_in,
                              void* d_out, int out_size, void* d_ws, size_t ws_size,
                              hipStream_t stream)
{
  const float* x  = (const float*)d_in[0];
  const float* Wq = (const float*)d_in[1];
  const float* bq = (const float*)d_in[2];
  const float* Wk = (const float*)d_in[3];
  const float* bk = (const float*)d_in[4];
  const float* Wv = (const float*)d_in[5];
  const float* pe = (const float*)d_in[6];
  float* ws = (float*)d_ws;
  float* out = (float*)d_out;

  prep_wx_kernel<<<dim3(544), dim3(256), 0, stream>>>(x, Wq, Wk, Wv, pe, ws);
  qkgemm_kernel<<<dim3(512), dim3(256), 0, stream>>>(ws, bq, bk);
  gsum_kernel<<<dim3(2048), dim3(256), 0, stream>>>(ws);
  diag_kernel<<<dim3(1152), dim3(256), 0, stream>>>(ws);
  out_kernel<<<dim3(256), dim3(256), 0, stream>>>(ws, out);
}

// Round 18
// 73.830 us; speedup vs baseline: 1.0802x; 1.0802x over previous
//
#include <hip/hip_runtime.h>
#include <hip/hip_bf16.h>
#include <math.h>

#define B 4
#define L 1024
#define D 256
#define H 8
#define HD 64

// workspace layout (float offsets)
#define KB_OFF  1048576                // Q bf16 [0, KB_OFF) floats
#define VR_OFF  2097152                // K bf16 [KB_OFF, VR_OFF); vr fp32 here
#define TP_OFF  (VR_OFF + 32768)       // Tpart fp32 [hb][qt 32][1024] (4 MB)
#define XP_OFF  (TP_OFF + 1048576)     // xpe bf16 [4096][256]
#define WT_OFF  (XP_OFF + 524288)      // WT bf16 [1024][256]
// total floats: WT_OFF + 131072 = 3833856 (~15.3 MB)

typedef short short8 __attribute__((ext_vector_type(8)));
typedef float f32x16 __attribute__((ext_vector_type(16)));

__device__ __forceinline__ unsigned short f2bf(float f) {
  __hip_bfloat16 h = __float2bfloat16(f);
  return *reinterpret_cast<unsigned short*>(&h);
}

// ---------------------------------------------------------------------------
// prep_wx: Blocks 0..31: WT transpose. Blocks 32..543: XP = bf16(x+pe);
//          vr[hb][k] = sigmoid(x@Wv) reversed (plain fp32).
// ---------------------------------------------------------------------------
__global__ __launch_bounds__(256) void prep_wx_kernel(
    const float* __restrict__ x, const float* __restrict__ Wq,
    const float* __restrict__ Wk, const float* __restrict__ Wv,
    const float* __restrict__ pe, float* __restrict__ ws)
{
  const int tid = threadIdx.x;
  if (blockIdx.x < 32) {
    __shared__ float lds[32][257];
    const int c0 = blockIdx.x * 32;
    const float* W = (c0 < 512) ? Wq : Wk;
    const int cc = c0 & 511;
    const int c = tid & 31, dd = tid >> 5;
    for (int d0 = 0; d0 < 256; d0 += 8)
      lds[c][d0 + dd] = W[(d0 + dd) * 512 + cc + c];
    __syncthreads();
    __hip_bfloat16* WT = (__hip_bfloat16*)(ws + WT_OFF);
    for (int cl = 0; cl < 32; ++cl)
      WT[(c0 + cl) * 256 + tid] = __float2bfloat16(lds[cl][tid]);
    return;
  }

  __shared__ float xs[8][257];
  const int r0 = (blockIdx.x - 32) * 8;
  __hip_bfloat16* XP = (__hip_bfloat16*)(ws + XP_OFF);
  for (int idx = tid; idx < 2048; idx += 256) {
    int rr = idx >> 8, c = idx & 255;
    int gr = r0 + rr, l = gr & 1023;
    float xv = x[gr * 256 + c];
    xs[rr][c] = xv;
    XP[gr * 256 + c] = __float2bfloat16(xv + pe[l * 256 + c]);
  }
  __syncthreads();
  if (tid < 64) {
    int rr = tid >> 3, h = tid & 7;
    float acc = 0.f;
    for (int d = 0; d < 256; ++d) acc += xs[rr][d] * Wv[d * 8 + h];
    float v = 1.f / (1.f + __expf(-acc));
    int gr = r0 + rr;
    int b = gr >> 10, l = gr & 1023;
    ws[VR_OFF + (h * 4 + b) * 1024 + (1023 - l)] = v;
  }
}

// ---------------------------------------------------------------------------
// qkgemm: Q|K = bf16(XP @ [Wq|Wk] + bias) via MFMA, written to [hb][l][64].
// ---------------------------------------------------------------------------
__global__ __launch_bounds__(256) void qkgemm_kernel(float* __restrict__ ws,
    const float* __restrict__ bq, const float* __restrict__ bk)
{
  const int tid = threadIdx.x;
  const int w = tid >> 6, lane = tid & 63;
  const int wid = blockIdx.x * 4 + w;
  const int lt = wid & 127;
  const int cp = wid >> 7;           // 0..15 (0..7 -> Q, 8..15 -> K)

  const __hip_bfloat16* XP = (const __hip_bfloat16*)(ws + XP_OFF);
  const __hip_bfloat16* WT = (const __hip_bfloat16*)(ws + WT_OFF);

  const int ln = (lt << 5) + (lane & 31);
  const int dlo = (lane >> 5) << 3;
  const int ca = (cp << 6) + (lane & 31);
  const __hip_bfloat16* xr = XP + ln * 256 + dlo;
  const __hip_bfloat16* ar = WT + ca * 256 + dlo;
  const __hip_bfloat16* br = ar + (32 * 256);

  f32x16 acca = {0.f,0.f,0.f,0.f,0.f,0.f,0.f,0.f,0.f,0.f,0.f,0.f,0.f,0.f,0.f,0.f};
  f32x16 accb = {0.f,0.f,0.f,0.f,0.f,0.f,0.f,0.f,0.f,0.f,0.f,0.f,0.f,0.f,0.f,0.f};
#pragma unroll
  for (int k = 0; k < 16; ++k) {
    short8 bf  = *(const short8*)(xr + k * 16);
    short8 afa = *(const short8*)(ar + k * 16);
    short8 afb = *(const short8*)(br + k * 16);
    acca = __builtin_amdgcn_mfma_f32_32x32x16_bf16(afa, bf, acca, 0, 0, 0);
    accb = __builtin_amdgcn_mfma_f32_32x32x16_bf16(afb, bf, accb, 0, 0, 0);
  }

  const int b = ln >> 10, l = ln & 1023;
  const int hq = cp & 7;
  const int hi4 = (lane >> 5) << 2;
  const float* bias = (cp < 8) ? bq : bk;
  const int cbase = hq << 6;
  __hip_bfloat16* base = (__hip_bfloat16*)ws + ((cp < 8) ? 0 : (size_t)KB_OFF * 2);
  __hip_bfloat16* dst = base + ((((size_t)(hq * 4 + b) << 10) + l) << 6);

#pragma unroll
  for (int q = 0; q < 4; ++q) {
    int hd0 = (q << 3) + hi4;
    float4 bv = *(const float4*)(bias + cbase + hd0);
    ushort4 pk;
    pk.x = f2bf(acca[4 * q + 0] + bv.x);
    pk.y = f2bf(acca[4 * q + 1] + bv.y);
    pk.z = f2bf(acca[4 * q + 2] + bv.z);
    pk.w = f2bf(acca[4 * q + 3] + bv.w);
    *(ushort4*)(dst + hd0) = pk;

    int hd1 = hd0 + 32;
    float4 bw = *(const float4*)(bias + cbase + hd1);
    ushort4 pk2;
    pk2.x = f2bf(accb[4 * q + 0] + bw.x);
    pk2.y = f2bf(accb[4 * q + 1] + bw.y);
    pk2.z = f2bf(accb[4 * q + 2] + bw.z);
    pk2.w = f2bf(accb[4 * q + 3] + bw.w);
    *(ushort4*)(dst + hd1) = pk2;
  }
}

// ---------------------------------------------------------------------------
// attn (FUSED gsum+diag, zero atomics): one block per (qt, hb), 4 waves.
// Phase 1: full 32-tile sweep (8/wave, 4-chain ILP) -> in-block denominator.
// Phase 2: wave w sweeps dt = w, w+4, ... (kt = qt+dt <= 31): MFMA ->
//   p = expf(S/8)*vr*inv -> r16 V-gather (plain ds_write + predicated
//   ds_read) -> PLAIN store into per-wave disjoint window Tb[w][dt*32+lane].
// Merge: Tpart[hb][qt][j] = sum_w Tb[w][j+31], plain stores.
// Grid 1024 = (qt 32) x (hb 32); hb = i&31 -> XCD-pinned. LDS ~35 KB.
// ---------------------------------------------------------------------------
__global__ __launch_bounds__(256) void attn_kernel(float* __restrict__ ws)
{
  __shared__ float V[4][64][17];    // 17.4 KB
  __shared__ float Tb[4][1056];     // 16.9 KB
  __shared__ float smerge[4][32];
  const int tid = threadIdx.x;
  const int w = tid >> 6, lane = tid & 63;
  const int i = blockIdx.x;
  const int hb = i & 31;
  const int qt = i >> 5;

  for (int idx = tid; idx < 4 * 1056; idx += 256) (&Tb[0][0])[idx] = 0.f;

  const __hip_bfloat16* Qb = (const __hip_bfloat16*)ws + ((size_t)hb << 16);
  const __hip_bfloat16* Kb = (const __hip_bfloat16*)(ws + KB_OFF) + ((size_t)hb << 16);
  const float* __restrict__ vr = ws + VR_OFF + (hb << 10);

  const int qrow = (qt << 5) + (lane & 31);
  const int dlo = (lane >> 5) << 3;
  const int coff = (lane >> 5) << 2;

  const __hip_bfloat16* qr = Qb + (qrow << 6) + dlo;
  short8 qf0 = *(const short8*)(qr);
  short8 qf1 = *(const short8*)(qr + 16);
  short8 qf2 = *(const short8*)(qr + 32);
  short8 qf3 = *(const short8*)(qr + 48);

#define GLOADK(kt, kf)                                                        \
  {                                                                           \
    const __hip_bfloat16* kr_ = Kb + ((((kt) << 5) + (lane & 31)) << 6) + dlo;\
    kf[0] = *(const short8*)(kr_);                                            \
    kf[1] = *(const short8*)(kr_ + 16);                                       \
    kf[2] = *(const short8*)(kr_ + 32);                                       \
    kf[3] = *(const short8*)(kr_ + 48);                                       \
  }

  // ---- phase 1: denominator, 8 tiles/wave in 2 rounds of 4 chains ----
  float s_part = 0.f;
#pragma unroll
  for (int t = 0; t < 2; ++t) {
    const int kt0 = w + (t << 2);    // chains: kt0, +8, +16, +24
    short8 kA[4], kB[4], kC[4], kD[4];
    GLOADK(kt0, kA);
    GLOADK(kt0 + 8, kB);
    GLOADK(kt0 + 16, kC);
    GLOADK(kt0 + 24, kD);
    f32x16 aA = {0.f,0.f,0.f,0.f,0.f,0.f,0.f,0.f,0.f,0.f,0.f,0.f,0.f,0.f,0.f,0.f};
    f32x16 aB = {0.f,0.f,0.f,0.f,0.f,0.f,0.f,0.f,0.f,0.f,0.f,0.f,0.f,0.f,0.f,0.f};
    f32x16 aC = {0.f,0.f,0.f,0.f,0.f,0.f,0.f,0.f,0.f,0.f,0.f,0.f,0.f,0.f,0.f,0.f};
    f32x16 aD = {0.f,0.f,0.f,0.f,0.f,0.f,0.f,0.f,0.f,0.f,0.f,0.f,0.f,0.f,0.f,0.f};
#pragma unroll
    for (int s = 0; s < 4; ++s) {
      short8 qs = (s == 0) ? qf0 : (s == 1) ? qf1 : (s == 2) ? qf2 : qf3;
      aA = __builtin_amdgcn_mfma_f32_32x32x16_bf16(kA[s], qs, aA, 0, 0, 0);
      aB = __builtin_amdgcn_mfma_f32_32x32x16_bf16(kB[s], qs, aB, 0, 0, 0);
      aC = __builtin_amdgcn_mfma_f32_32x32x16_bf16(kC[s], qs, aC, 0, 0, 0);
      aD = __builtin_amdgcn_mfma_f32_32x32x16_bf16(kD[s], qs, aD, 0, 0, 0);
    }
#pragma unroll
    for (int r = 0; r < 16; ++r) {
      s_part += __expf(aA[r] * 0.125f);
      s_part += __expf(aB[r] * 0.125f);
      s_part += __expf(aC[r] * 0.125f);
      s_part += __expf(aD[r] * 0.125f);
    }
  }
  s_part += __shfl_xor(s_part, 32);
  if (lane < 32) smerge[w][lane] = s_part;
  __syncthreads();   // also covers Tb zero-init
  const int q = lane & 31;
  const float inv = 1.f / (smerge[0][q] + smerge[1][q] + smerge[2][q] + smerge[3][q]);

  // ---- phase 2: upper-tri tiles, dt = w, w+4, ...; zero-atomic flush ----
  for (int dt = w; dt <= 31 - qt; dt += 4) {
    const int kt = qt + dt;
    short8 kf[4];
    GLOADK(kt, kf);
    f32x16 acc = {0.f,0.f,0.f,0.f,0.f,0.f,0.f,0.f,0.f,0.f,0.f,0.f,0.f,0.f,0.f,0.f};
    acc = __builtin_amdgcn_mfma_f32_32x32x16_bf16(kf[0], qf0, acc, 0, 0, 0);
    acc = __builtin_amdgcn_mfma_f32_32x32x16_bf16(kf[1], qf1, acc, 0, 0, 0);
    acc = __builtin_amdgcn_mfma_f32_32x32x16_bf16(kf[2], qf2, acc, 0, 0, 0);
    acc = __builtin_amdgcn_mfma_f32_32x32x16_bf16(kf[3], qf3, acc, 0, 0, 0);

    const float* vb = vr + (kt << 5) + coff;
    float4 v0 = *(const float4*)(vb);
    float4 v1 = *(const float4*)(vb + 8);
    float4 v2 = *(const float4*)(vb + 16);
    float4 v3 = *(const float4*)(vb + 24);
#pragma unroll
    for (int r = 0; r < 16; ++r) {
      float vv = (r < 4) ? (&v0.x)[r] : (r < 8) ? (&v1.x)[r - 4]
               : (r < 12) ? (&v2.x)[r - 8] : (&v3.x)[r - 12];
      V[w][lane][r] = __expf(acc[r] * 0.125f) * vv * inv;
    }
    // r16 gather: lane s sums all (lane_src, r) mapping to slot dt*32+s-31.
    float accg = 0.f;
#pragma unroll
    for (int hi = 0; hi < 2; ++hi)
#pragma unroll
      for (int r = 0; r < 16; ++r) {
        int l = (hi << 2) + (r & 3) + ((r >> 2) << 3) + 31 - lane;
        if (l >= 0 && l < 32) accg += V[w][(hi << 5) + l][r];
      }
    Tb[w][(dt << 5) + lane] = accg;   // disjoint per-wave window: plain store
  }
  __syncthreads();

  // merge: Tpart[hb][qt][j] = sum_w Tb[w][j+31]  (j+31 >= 31 skips j<0 slots)
  float* dst = ws + TP_OFF + (((size_t)hb << 5) + qt) * 1024;
  for (int idx = tid; idx < 1024; idx += 256)
    dst[idx] = Tb[0][idx + 31] + Tb[1][idx + 31] + Tb[2][idx + 31] + Tb[3][idx + 31];
}

// ---------------------------------------------------------------------------
// out: T[hb][j] = sum_qt Tpart[hb][qt][j]; out[b,j,h] = window3(T)/cnt.
// Grid 256 = (jc 8) x (hb 32).
// ---------------------------------------------------------------------------
__global__ __launch_bounds__(256) void out_kernel(const float* __restrict__ ws,
                                                  float* __restrict__ out)
{
  __shared__ float s[130];
  const int tid = threadIdx.x;
  const int i = blockIdx.x;
  const int hb = i & 31;
  const int jc = i >> 5;
  const int j0 = jc << 7;
  const float* TP = ws + TP_OFF + ((size_t)hb << 15);

  if (tid < 130) {
    int j = j0 + tid - 1;
    float acc = 0.f;
    if (j >= 0 && j < 1024) {
#pragma unroll 8
      for (int qt = 0; qt < 32; ++qt) acc += TP[(qt << 10) + j];
    }
    s[tid] = acc;
  }
  __syncthreads();
  if (tid < 128) {
    int j = j0 + tid;
    float cnt = (j == 0 || j == 1023) ? 2.f : 3.f;
    float v = (s[tid] + s[tid + 1] + s[tid + 2]) / cnt;
    int h = hb >> 2, b = hb & 3;
    out[(((b << 10) + j) << 3) + h] = v;
  }
}

extern "C" void kernel_launch(void* const* d_in, const int* in_sizes, int n_in,
                              void* d_out, int out_size, void* d_ws, size_t ws_size,
                              hipStream_t stream)
{
  const float* x  = (const float*)d_in[0];
  const float* Wq = (const float*)d_in[1];
  const float* bq = (const float*)d_in[2];
  const float* Wk = (const float*)d_in[3];
  const float* bk = (const float*)d_in[4];
  const float* Wv = (const float*)d_in[5];
  const float* pe = (const float*)d_in[6];
  float* ws = (float*)d_ws;
  float* out = (float*)d_out;

  prep_wx_kernel<<<dim3(544), dim3(256), 0, stream>>>(x, Wq, Wk, Wv, pe, ws);
  qkgemm_kernel<<<dim3(512), dim3(256), 0, stream>>>(ws, bq, bk);
  attn_kernel<<<dim3(1024), dim3(256), 0, stream>>>(ws);
  out_kernel<<<dim3(256), dim3(256), 0, stream>>>(ws, out);
}

// Round 19
// 72.579 us; speedup vs baseline: 1.0989x; 1.0172x over previous
//
#include <hip/hip_runtime.h>
#include <hip/hip_bf16.h>
#include <math.h>

#define B 4
#define L 1024
#define D 256
#define H 8
#define HD 64

// workspace layout (float offsets)
#define KB_OFF  1048576                // Q bf16 [0, KB_OFF) floats
#define VR_OFF  2097152                // K bf16 [KB_OFF, VR_OFF); vr fp32 here
#define TP_OFF  (VR_OFF + 32768)       // Tpart fp32 [hb][qt 32][1024] (4 MB)
#define XP_OFF  (TP_OFF + 1048576)     // xpe bf16 [4096][256]
#define WT_OFF  (XP_OFF + 524288)      // WT bf16 [1024][256]
// total floats: WT_OFF + 131072 = 3833856 (~15.3 MB)

typedef short short8 __attribute__((ext_vector_type(8)));
typedef float f32x16 __attribute__((ext_vector_type(16)));

__device__ __forceinline__ unsigned short f2bf(float f) {
  __hip_bfloat16 h = __float2bfloat16(f);
  return *reinterpret_cast<unsigned short*>(&h);
}

// ---------------------------------------------------------------------------
// prep_wx: Blocks 0..31: WT transpose. Blocks 32..543: XP = bf16(x+pe);
//          vr[hb][k] = sigmoid(x@Wv) reversed (parallel: 4 thr per (row,h)).
// ---------------------------------------------------------------------------
__global__ __launch_bounds__(256) void prep_wx_kernel(
    const float* __restrict__ x, const float* __restrict__ Wq,
    const float* __restrict__ Wk, const float* __restrict__ Wv,
    const float* __restrict__ pe, float* __restrict__ ws)
{
  const int tid = threadIdx.x;
  if (blockIdx.x < 32) {
    __shared__ float lds[32][257];
    const int c0 = blockIdx.x * 32;
    const float* W = (c0 < 512) ? Wq : Wk;
    const int cc = c0 & 511;
    const int c = tid & 31, dd = tid >> 5;
    for (int d0 = 0; d0 < 256; d0 += 8)
      lds[c][d0 + dd] = W[(d0 + dd) * 512 + cc + c];
    __syncthreads();
    __hip_bfloat16* WT = (__hip_bfloat16*)(ws + WT_OFF);
    for (int cl = 0; cl < 32; ++cl)
      WT[(c0 + cl) * 256 + tid] = __float2bfloat16(lds[cl][tid]);
    return;
  }

  __shared__ float xs[8][257];
  const int r0 = (blockIdx.x - 32) * 8;
  __hip_bfloat16* XP = (__hip_bfloat16*)(ws + XP_OFF);
  for (int idx = tid; idx < 2048; idx += 256) {
    int rr = idx >> 8, c = idx & 255;
    int gr = r0 + rr, l = gr & 1023;
    float xv = x[gr * 256 + c];
    xs[rr][c] = xv;
    XP[gr * 256 + c] = __float2bfloat16(xv + pe[l * 256 + c]);
  }
  __syncthreads();
  {
    // 4 threads per (rr, h): tid = rr*32 + h*4 + t4 (groups wave-aligned)
    int rr = tid >> 5, h = (tid >> 2) & 7, t4 = tid & 3;
    float acc = 0.f;
    const int d0 = t4 << 6;
#pragma unroll 16
    for (int d = 0; d < 64; ++d) acc += xs[rr][d0 + d] * Wv[(d0 + d) * 8 + h];
    acc += __shfl_down(acc, 1, 4);
    acc += __shfl_down(acc, 2, 4);
    if (t4 == 0) {
      float v = 1.f / (1.f + __expf(-acc));
      int gr = r0 + rr;
      int b = gr >> 10, l = gr & 1023;
      ws[VR_OFF + (h * 4 + b) * 1024 + (1023 - l)] = v;
    }
  }
}

// ---------------------------------------------------------------------------
// qkgemm: Q|K = bf16(XP @ [Wq|Wk] + bias) via MFMA, written to [hb][l][64].
// ---------------------------------------------------------------------------
__global__ __launch_bounds__(256) void qkgemm_kernel(float* __restrict__ ws,
    const float* __restrict__ bq, const float* __restrict__ bk)
{
  const int tid = threadIdx.x;
  const int w = tid >> 6, lane = tid & 63;
  const int wid = blockIdx.x * 4 + w;
  const int lt = wid & 127;
  const int cp = wid >> 7;           // 0..15 (0..7 -> Q, 8..15 -> K)

  const __hip_bfloat16* XP = (const __hip_bfloat16*)(ws + XP_OFF);
  const __hip_bfloat16* WT = (const __hip_bfloat16*)(ws + WT_OFF);

  const int ln = (lt << 5) + (lane & 31);
  const int dlo = (lane >> 5) << 3;
  const int ca = (cp << 6) + (lane & 31);
  const __hip_bfloat16* xr = XP + ln * 256 + dlo;
  const __hip_bfloat16* ar = WT + ca * 256 + dlo;
  const __hip_bfloat16* br = ar + (32 * 256);

  f32x16 acca = {0.f,0.f,0.f,0.f,0.f,0.f,0.f,0.f,0.f,0.f,0.f,0.f,0.f,0.f,0.f,0.f};
  f32x16 accb = {0.f,0.f,0.f,0.f,0.f,0.f,0.f,0.f,0.f,0.f,0.f,0.f,0.f,0.f,0.f,0.f};
#pragma unroll
  for (int k = 0; k < 16; ++k) {
    short8 bf  = *(const short8*)(xr + k * 16);
    short8 afa = *(const short8*)(ar + k * 16);
    short8 afb = *(const short8*)(br + k * 16);
    acca = __builtin_amdgcn_mfma_f32_32x32x16_bf16(afa, bf, acca, 0, 0, 0);
    accb = __builtin_amdgcn_mfma_f32_32x32x16_bf16(afb, bf, accb, 0, 0, 0);
  }

  const int b = ln >> 10, l = ln & 1023;
  const int hq = cp & 7;
  const int hi4 = (lane >> 5) << 2;
  const float* bias = (cp < 8) ? bq : bk;
  const int cbase = hq << 6;
  __hip_bfloat16* base = (__hip_bfloat16*)ws + ((cp < 8) ? 0 : (size_t)KB_OFF * 2);
  __hip_bfloat16* dst = base + ((((size_t)(hq * 4 + b) << 10) + l) << 6);

#pragma unroll
  for (int q = 0; q < 4; ++q) {
    int hd0 = (q << 3) + hi4;
    float4 bv = *(const float4*)(bias + cbase + hd0);
    ushort4 pk;
    pk.x = f2bf(acca[4 * q + 0] + bv.x);
    pk.y = f2bf(acca[4 * q + 1] + bv.y);
    pk.z = f2bf(acca[4 * q + 2] + bv.z);
    pk.w = f2bf(acca[4 * q + 3] + bv.w);
    *(ushort4*)(dst + hd0) = pk;

    int hd1 = hd0 + 32;
    float4 bw = *(const float4*)(bias + cbase + hd1);
    ushort4 pk2;
    pk2.x = f2bf(accb[4 * q + 0] + bw.x);
    pk2.y = f2bf(accb[4 * q + 1] + bw.y);
    pk2.z = f2bf(accb[4 * q + 2] + bw.z);
    pk2.w = f2bf(accb[4 * q + 3] + bw.w);
    *(ushort4*)(dst + hd1) = pk2;
  }
}

// ---------------------------------------------------------------------------
// attn (fused, zero atomics): one block per (qt, hb), 4 waves.
// Phase 1: full 32-tile sweep (8/wave, 4-chain, 4 exp accumulators).
// Phase 2: wave w sweeps dt in PAIRS (dt, dt+4): 2-chain loads+MFMA, then
//   two V-gathers -> plain stores into disjoint Tb[w] windows.
// Merge: Tpart[hb][qt][j] = sum_w Tb[w][j+31].
// Grid 1024 = (qt 32) x (hb 32); hb = i&31 -> XCD-pinned.
// ---------------------------------------------------------------------------
__global__ __launch_bounds__(256) void attn_kernel(float* __restrict__ ws)
{
  __shared__ float V[4][64][17];    // 17.4 KB
  __shared__ float Tb[4][1056];     // 16.9 KB
  __shared__ float smerge[4][32];
  const int tid = threadIdx.x;
  const int w = tid >> 6, lane = tid & 63;
  const int i = blockIdx.x;
  const int hb = i & 31;
  const int qt = i >> 5;

  for (int idx = tid; idx < 4 * 1056; idx += 256) (&Tb[0][0])[idx] = 0.f;

  const __hip_bfloat16* Qb = (const __hip_bfloat16*)ws + ((size_t)hb << 16);
  const __hip_bfloat16* Kb = (const __hip_bfloat16*)(ws + KB_OFF) + ((size_t)hb << 16);
  const float* __restrict__ vr = ws + VR_OFF + (hb << 10);

  const int qrow = (qt << 5) + (lane & 31);
  const int dlo = (lane >> 5) << 3;
  const int coff = (lane >> 5) << 2;

  const __hip_bfloat16* qr = Qb + (qrow << 6) + dlo;
  short8 qf0 = *(const short8*)(qr);
  short8 qf1 = *(const short8*)(qr + 16);
  short8 qf2 = *(const short8*)(qr + 32);
  short8 qf3 = *(const short8*)(qr + 48);

#define GLOADK(kt, kf)                                                        \
  {                                                                           \
    const __hip_bfloat16* kr_ = Kb + ((((kt) << 5) + (lane & 31)) << 6) + dlo;\
    kf[0] = *(const short8*)(kr_);                                            \
    kf[1] = *(const short8*)(kr_ + 16);                                       \
    kf[2] = *(const short8*)(kr_ + 32);                                       \
    kf[3] = *(const short8*)(kr_ + 48);                                       \
  }

  // ---- phase 1: denominator, 8 tiles/wave, 4 chains, 4 exp accumulators ----
  float sp0 = 0.f, sp1 = 0.f, sp2 = 0.f, sp3 = 0.f;
#pragma unroll
  for (int t = 0; t < 2; ++t) {
    const int kt0 = w + (t << 2);    // chains: kt0, +8, +16, +24
    short8 kA[4], kB[4], kC[4], kD[4];
    GLOADK(kt0, kA);
    GLOADK(kt0 + 8, kB);
    GLOADK(kt0 + 16, kC);
    GLOADK(kt0 + 24, kD);
    f32x16 aA = {0.f,0.f,0.f,0.f,0.f,0.f,0.f,0.f,0.f,0.f,0.f,0.f,0.f,0.f,0.f,0.f};
    f32x16 aB = {0.f,0.f,0.f,0.f,0.f,0.f,0.f,0.f,0.f,0.f,0.f,0.f,0.f,0.f,0.f,0.f};
    f32x16 aC = {0.f,0.f,0.f,0.f,0.f,0.f,0.f,0.f,0.f,0.f,0.f,0.f,0.f,0.f,0.f,0.f};
    f32x16 aD = {0.f,0.f,0.f,0.f,0.f,0.f,0.f,0.f,0.f,0.f,0.f,0.f,0.f,0.f,0.f,0.f};
#pragma unroll
    for (int s = 0; s < 4; ++s) {
      short8 qs = (s == 0) ? qf0 : (s == 1) ? qf1 : (s == 2) ? qf2 : qf3;
      aA = __builtin_amdgcn_mfma_f32_32x32x16_bf16(kA[s], qs, aA, 0, 0, 0);
      aB = __builtin_amdgcn_mfma_f32_32x32x16_bf16(kB[s], qs, aB, 0, 0, 0);
      aC = __builtin_amdgcn_mfma_f32_32x32x16_bf16(kC[s], qs, aC, 0, 0, 0);
      aD = __builtin_amdgcn_mfma_f32_32x32x16_bf16(kD[s], qs, aD, 0, 0, 0);
    }
#pragma unroll
    for (int r = 0; r < 16; ++r) {
      sp0 += __expf(aA[r] * 0.125f);
      sp1 += __expf(aB[r] * 0.125f);
      sp2 += __expf(aC[r] * 0.125f);
      sp3 += __expf(aD[r] * 0.125f);
    }
  }
  float s_part = (sp0 + sp1) + (sp2 + sp3);
  s_part += __shfl_xor(s_part, 32);
  if (lane < 32) smerge[w][lane] = s_part;
  __syncthreads();   // also covers Tb zero-init
  const int q = lane & 31;
  const float inv = 1.f / (smerge[0][q] + smerge[1][q] + smerge[2][q] + smerge[3][q]);

  // per-tile epilogue: p -> V -> gather -> Tb window (zero atomics)
#define FLUSH(dt_, acc_)                                                      \
  {                                                                           \
    const int kt_ = qt + (dt_);                                               \
    const float* vb_ = vr + (kt_ << 5) + coff;                                \
    float4 v0_ = *(const float4*)(vb_);                                       \
    float4 v1_ = *(const float4*)(vb_ + 8);                                   \
    float4 v2_ = *(const float4*)(vb_ + 16);                                  \
    float4 v3_ = *(const float4*)(vb_ + 24);                                  \
    _Pragma("unroll")                                                         \
    for (int r = 0; r < 16; ++r) {                                            \
      float vv_ = (r < 4) ? (&v0_.x)[r] : (r < 8) ? (&v1_.x)[r - 4]           \
                : (r < 12) ? (&v2_.x)[r - 8] : (&v3_.x)[r - 12];              \
      V[w][lane][r] = __expf(acc_[r] * 0.125f) * vv_ * inv;                   \
    }                                                                         \
    float accg_ = 0.f;                                                        \
    _Pragma("unroll")                                                         \
    for (int hi = 0; hi < 2; ++hi)                                            \
      _Pragma("unroll")                                                       \
      for (int r = 0; r < 16; ++r) {                                          \
        int l_ = (hi << 2) + (r & 3) + ((r >> 2) << 3) + 31 - lane;           \
        if (l_ >= 0 && l_ < 32) accg_ += V[w][(hi << 5) + l_][r];             \
      }                                                                       \
    Tb[w][((dt_) << 5) + lane] = accg_;                                       \
  }

  // ---- phase 2: paired tiles (dt, dt+4) ----
  const int dtmax = 31 - qt;
  for (int dt = w; dt <= dtmax; dt += 8) {
    const int dt2 = dt + 4;
    const bool has2 = (dt2 <= dtmax);
    const int kta = qt + dt;
    const int ktb = qt + (has2 ? dt2 : dt);   // clamp: safe address
    short8 ka[4], kb[4];
    GLOADK(kta, ka);
    GLOADK(ktb, kb);
    f32x16 acca = {0.f,0.f,0.f,0.f,0.f,0.f,0.f,0.f,0.f,0.f,0.f,0.f,0.f,0.f,0.f,0.f};
    f32x16 accb = {0.f,0.f,0.f,0.f,0.f,0.f,0.f,0.f,0.f,0.f,0.f,0.f,0.f,0.f,0.f,0.f};
    acca = __builtin_amdgcn_mfma_f32_32x32x16_bf16(ka[0], qf0, acca, 0, 0, 0);
    accb = __builtin_amdgcn_mfma_f32_32x32x16_bf16(kb[0], qf0, accb, 0, 0, 0);
    acca = __builtin_amdgcn_mfma_f32_32x32x16_bf16(ka[1], qf1, acca, 0, 0, 0);
    accb = __builtin_amdgcn_mfma_f32_32x32x16_bf16(kb[1], qf1, accb, 0, 0, 0);
    acca = __builtin_amdgcn_mfma_f32_32x32x16_bf16(ka[2], qf2, acca, 0, 0, 0);
    accb = __builtin_amdgcn_mfma_f32_32x32x16_bf16(kb[2], qf2, accb, 0, 0, 0);
    acca = __builtin_amdgcn_mfma_f32_32x32x16_bf16(ka[3], qf3, acca, 0, 0, 0);
    accb = __builtin_amdgcn_mfma_f32_32x32x16_bf16(kb[3], qf3, accb, 0, 0, 0);
    FLUSH(dt, acca);
    if (has2) FLUSH(dt2, accb);
  }
  __syncthreads();

  // merge: Tpart[hb][qt][j] = sum_w Tb[w][j+31]
  float* dst = ws + TP_OFF + (((size_t)hb << 5) + qt) * 1024;
  for (int idx = tid; idx < 1024; idx += 256)
    dst[idx] = Tb[0][idx + 31] + Tb[1][idx + 31] + Tb[2][idx + 31] + Tb[3][idx + 31];
}

// ---------------------------------------------------------------------------
// out: T[hb][j] = sum_qt Tpart[hb][qt][j]; out[b,j,h] = window3(T)/cnt.
// Grid 256 = (jc 8) x (hb 32).
// ---------------------------------------------------------------------------
__global__ __launch_bounds__(256) void out_kernel(const float* __restrict__ ws,
                                                  float* __restrict__ out)
{
  __shared__ float s[130];
  const int tid = threadIdx.x;
  const int i = blockIdx.x;
  const int hb = i & 31;
  const int jc = i >> 5;
  const int j0 = jc << 7;
  const float* TP = ws + TP_OFF + ((size_t)hb << 15);

  if (tid < 130) {
    int j = j0 + tid - 1;
    float acc = 0.f;
    if (j >= 0 && j < 1024) {
#pragma unroll 8
      for (int qt = 0; qt < 32; ++qt) acc += TP[(qt << 10) + j];
    }
    s[tid] = acc;
  }
  __syncthreads();
  if (tid < 128) {
    int j = j0 + tid;
    float cnt = (j == 0 || j == 1023) ? 2.f : 3.f;
    float v = (s[tid] + s[tid + 1] + s[tid + 2]) / cnt;
    int h = hb >> 2, b = hb & 3;
    out[(((b << 10) + j) << 3) + h] = v;
  }
}

extern "C" void kernel_launch(void* const* d_in, const int* in_sizes, int n_in,
                              void* d_out, int out_size, void* d_ws, size_t ws_size,
                              hipStream_t stream)
{
  const float* x  = (const float*)d_in[0];
  const float* Wq = (const float*)d_in[1];
  const float* bq = (const float*)d_in[2];
  const float* Wk = (const float*)d_in[3];
  const float* bk = (const float*)d_in[4];
  const float* Wv = (const float*)d_in[5];
  const float* pe = (const float*)d_in[6];
  float* ws = (float*)d_ws;
  float* out = (float*)d_out;

  prep_wx_kernel<<<dim3(544), dim3(256), 0, stream>>>(x, Wq, Wk, Wv, pe, ws);
  qkgemm_kernel<<<dim3(512), dim3(256), 0, stream>>>(ws, bq, bk);
  attn_kernel<<<dim3(1024), dim3(256), 0, stream>>>(ws);
  out_kernel<<<dim3(256), dim3(256), 0, stream>>>(ws, out);
}